// Round 5
// baseline (102.259 us; speedup 1.0000x reference)
//
#include <hip/hip_runtime.h>
#include <cmath>

#define DD   10
#define FF   32
#define OUTN 32
#define PPW  2          // (b,v) pairs per wave
#define NW   4          // waves per block
#define NT   (NW * 64)
#define PAD  36         // padded row stride in floats (144 B, keeps b128 16B-aligned)

typedef float f32x4 __attribute__((ext_vector_type(4)));

// Kernel 1: summed[b,v,f] = sum_d inputs[b,v,d,f]  (f32x4, nt loads)
__global__ __launch_bounds__(256) void sum_d4_kernel(
    const f32x4* __restrict__ in, f32x4* __restrict__ out, int n4) {
    int idx = blockIdx.x * 256 + threadIdx.x;
    if (idx >= n4) return;
    int f4 = idx & 7;
    int bv = idx >> 3;
    const f32x4* p = in + (size_t)bv * (DD * 8) + f4;
    f32x4 s = __builtin_nontemporal_load(p);
#pragma unroll
    for (int d = 1; d < DD; ++d) s += __builtin_nontemporal_load(p + d * 8);
    out[idx] = s;   // re-read by gat: keep cacheable
}

__device__ __forceinline__ float dpp_add(float v, const int ctrl) {
    int x;
    switch (ctrl) {  // ctrl must be literal per builtin; switch keeps it constant
        case 0x121: x = __builtin_amdgcn_update_dpp(0, __float_as_int(v), 0x121, 0xF, 0xF, true); break;
        case 0x122: x = __builtin_amdgcn_update_dpp(0, __float_as_int(v), 0x122, 0xF, 0xF, true); break;
        case 0x124: x = __builtin_amdgcn_update_dpp(0, __float_as_int(v), 0x124, 0xF, 0xF, true); break;
        default:    x = __builtin_amdgcn_update_dpp(0, __float_as_int(v), 0x128, 0xF, 0xF, true); break;
    }
    return v + __int_as_float(x);
}

// sum over the 32-lane half this lane belongs to (rows 0..1 or 2..3 of the wave)
__device__ __forceinline__ float half_reduce32(float v) {
    v = dpp_add(v, 0x121);   // row_ror:1  (16-lane cyclic reduce)
    v = dpp_add(v, 0x122);   // row_ror:2
    v = dpp_add(v, 0x124);   // row_ror:4
    v = dpp_add(v, 0x128);   // row_ror:8
    int w = __builtin_amdgcn_ds_swizzle(__float_as_int(v), 0x401F);  // lane ^ 16
    return v + __int_as_float(w);
}

// Kernel 2: one (b,v) pair per 64-lane wave; lane = (row-parity hi, output o).
__global__ __launch_bounds__(NT) void gat_kernel(
    const float* __restrict__ summed,
    const float* __restrict__ init,
    const float* __restrict__ mask,
    const float* __restrict__ Wk,
    const float* __restrict__ Wb,
    const float* __restrict__ Ak,
    const int* __restrict__ adj,
    const int* __restrict__ mask_index_p,
    float* __restrict__ out,
    int B, int V) {
    __shared__ float sGI[NW][PPW][DD][PAD];     // 11.5 KB

    const int t    = threadIdx.x;
    const int lane = t & 63;
    const int w    = t >> 6;
    const int o    = lane & 31;                 // output channel
    const int hi   = lane >> 5;                 // row parity
    const int BV   = B * V;
    const int mask_index = *mask_index_p;
    const int vo   = hi * FF + o;               // element voffset for init/out rows

    // W column + bias + a for this lane's o (L1-hot, imm offsets)
    float Wc[FF];
#pragma unroll
    for (int f = 0; f < FF; ++f) Wc[f] = Wk[f * OUTN + o];
    const float bias_o = Wb[o];
    const float a_o    = Ak[o];

    const int pair0 = (blockIdx.x * NW + w) * PPW;

#pragma unroll
    for (int pp = 0; pp < PPW; ++pp) {
        int bv = pair0 + pp;                    // wave-uniform
        const bool valid = bv < BV;
        if (!valid) bv = BV - 1;
        const int b = bv / V;                   // uniform div (SALU)

        // ---- adj + mask: uniform -> scalar loads ----
        const int*   ap = adj  + (size_t)bv * DD;
        const float* mp = mask + (size_t)bv * DD;
        int   av[DD];
        float zm[DD];
#pragma unroll
        for (int j = 0; j < DD; ++j) { av[j] = ap[j]; zm[j] = 1.f - mp[j]; }

        // ---- gathers: 5 insts, 2 rows each (256 B coalesced) ----
        const float* sb = summed + (size_t)b * V * FF;
        float gv[5];
#pragma unroll
        for (int g = 0; g < 5; ++g) {
            int a0 = av[2 * g], a1 = av[2 * g + 1];
            int c0 = a0 < 0 ? 0 : (a0 >= V ? V - 1 : a0);   // JAX clamp
            int c1 = a1 < 0 ? 0 : (a1 >= V ? V - 1 : a1);
            int r  = hi ? c1 : c0;
            gv[g] = sb[(size_t)r * FF + o];
        }

        // ---- init: 5 insts, 2 rows each, nontemporal ----
        const float* ip = init + (size_t)bv * (DD * FF);
        float iv[5];
#pragma unroll
        for (int g = 0; g < 5; ++g)
            iv[g] = __builtin_nontemporal_load(ip + g * 2 * FF + vo);

        // ---- gi = szg*g + zm*ini -> LDS (row r = 2g+hi, padded stride) ----
        float* gbuf = &sGI[w][pp][0][0];
        float zmr[5];
#pragma unroll
        for (int g = 0; g < 5; ++g) {
            float z0 = zm[2 * g], z1 = zm[2 * g + 1];
            zmr[g] = hi ? z1 : z0;
            bool m0 = (av[2 * g] == mask_index), m1 = (av[2 * g + 1] == mask_index);
            float szg = (hi ? m1 : m0) ? 0.f : zmr[g];
            gbuf[(2 * g + hi) * PAD + o] = fmaf(szg, gv[g], zmr[g] * iv[g]);
        }
        // wave-local LDS: compiler-inserted lgkmcnt, no barrier

        // ---- dense F->OUT + relu (b128 broadcast reads, 2 banks/inst) ----
        float T[5];
#pragma unroll
        for (int g = 0; g < 5; ++g) {
            const float* rp = gbuf + (2 * g + hi) * PAD;
            float acc = bias_o;
#pragma unroll
            for (int q = 0; q < 8; ++q) {
                f32x4 x = *(const f32x4*)(rp + q * 4);
                acc = fmaf(x.x, Wc[4 * q + 0], acc);
                acc = fmaf(x.y, Wc[4 * q + 1], acc);
                acc = fmaf(x.z, Wc[4 * q + 2], acc);
                acc = fmaf(x.w, Wc[4 * q + 3], acc);
            }
            T[g] = fmaxf(acc, 0.f) * zmr[g];
        }

        // ---- attn dot: DPP ror-reduce within 32-lane half ----
        float awo[5];
#pragma unroll
        for (int g = 0; g < 5; ++g) {
            float s = half_reduce32(T[g] * a_o);
            awo[g] = s - 1e7f * (1.f - zmr[g]);
        }
        // other parity's aw via cross-half shuffle
        float awx[5];
#pragma unroll
        for (int g = 0; g < 5; ++g) awx[g] = __shfl_xor(awo[g], 32);

        // ---- softmax over D=10 (redundant per lane) ----
        float mx = awo[0];
#pragma unroll
        for (int g = 1; g < 5; ++g) mx = fmaxf(mx, awo[g]);
#pragma unroll
        for (int g = 0; g < 5; ++g) mx = fmaxf(mx, awx[g]);
        float den = 0.f, eo[5];
#pragma unroll
        for (int g = 0; g < 5; ++g) { eo[g] = __expf(awo[g] - mx); den += eo[g]; }
#pragma unroll
        for (int g = 0; g < 5; ++g) den += __expf(awx[g] - mx);
        const float inv = 1.f / den;

        // ---- out = coef * T, 5 nt stores, 2 rows each ----
        if (valid) {
            float* op = out + (size_t)bv * (DD * OUTN);
#pragma unroll
            for (int g = 0; g < 5; ++g)
                __builtin_nontemporal_store((eo[g] * inv) * T[g], op + g * 2 * FF + vo);
        }
    }
}

extern "C" void kernel_launch(void* const* d_in, const int* in_sizes, int n_in,
                              void* d_out, int out_size, void* d_ws, size_t ws_size,
                              hipStream_t stream) {
    const float* inputs = (const float*)d_in[0];
    const float* init   = (const float*)d_in[1];
    const float* mask   = (const float*)d_in[2];
    const float* Wk     = (const float*)d_in[3];
    const float* Wb     = (const float*)d_in[4];
    const float* Ak     = (const float*)d_in[5];
    const int*   adj    = (const int*)d_in[6];
    const int*   mip    = (const int*)d_in[7];

    const int B   = 4;
    const int BVD = in_sizes[2];          // B*V*D
    const int V   = BVD / (B * DD);
    const int BV  = B * V;

    float* summed = (float*)d_ws;         // B*V*FF floats = 10.24 MB
    int n4 = BV * (FF / 4);
    hipLaunchKernelGGL(sum_d4_kernel, dim3((n4 + 255) / 256), dim3(256), 0, stream,
                       (const f32x4*)inputs, (f32x4*)summed, n4);
    int pairs_per_block = NW * PPW;
    hipLaunchKernelGGL(gat_kernel, dim3((BV + pairs_per_block - 1) / pairs_per_block),
                       dim3(NT), 0, stream,
                       summed, init, mask, Wk, Wb, Ak, adj, mip, (float*)d_out, B, V);
}